// Round 10
// baseline (147.962 us; speedup 1.0000x reference)
//
#include <hip/hip_runtime.h>
#include <math.h>

#define BB 16
#define NN 2048
#define MM 16
#define SS 128

__constant__ const float kFourPi = 12.566370614359172f;

// ---------------------------------------------------------------------------
// Kernel A: grid (256 bm, 4 n-chunks) x 256 threads, 4 blocks/CU.
// ZERO LDS, ZERO barriers. Each thread: 2 pcl points in regs (n0+tid,
// n0+tid+256), loops all 128 s in 4 groups of 32. prim is read through a
// wave-uniform pointer -> scalar loads (s_load, scalar cache). e = d/2 via
// dot expansion. d1 (e-scale) finished in-block, coalesced write. d2 via
// R8-verified fold32 (dup x2 per lane) + uint-punned atomicMin into
// d2min[128][256] (values >= 0; any s-permutation inside the fold is
// harmless: d2 is summed over s). Block (0,0) zeroes kernel B's counter.
// ---------------------------------------------------------------------------
__global__ __launch_bounds__(256, 4) void dist_kernel(
    const float* __restrict__ pcl,     // (B,N,M,3)
    const float* __restrict__ prim,    // (B,M,S,3)
    float* __restrict__ d1,            // [256][2048] (e-scale)
    unsigned int* __restrict__ d2min,  // [128][256]  (e-scale, uint-punned)
    unsigned int* __restrict__ counter)
{
    const int bm    = blockIdx.x;
    const int chunk = blockIdx.y;
    const int b     = bm >> 4;
    const int m     = bm & 15;
    const int tid   = threadIdx.x;
    const int lane  = tid & 63;

    if (bm == 0 && chunk == 0 && tid == 0)
        __hip_atomic_store(counter, 0u, __ATOMIC_RELAXED, __HIP_MEMORY_SCOPE_AGENT);

    const int n0 = chunk * 512;
    // two pcl points per thread, scattered 12B loads (read exactly once)
    const float* q0p = pcl + ((size_t)(b * NN + n0 + tid) * MM + m) * 3;
    const float* q1p = q0p + (size_t)256 * MM * 3;
    const float q0x = q0p[0], q0y = q0p[1], q0z = q0p[2];
    const float q1x = q1p[0], q1y = q1p[1], q1z = q1p[2];
    const float hq0 = 0.5f * (q0x * q0x + q0y * q0y + q0z * q0z);
    const float hq1 = 0.5f * (q1x * q1x + q1y * q1y + q1z * q1z);

    float d1m0 = 3.0e38f, d1m1 = 3.0e38f;

#pragma unroll
    for (int g = 0; g < 4; ++g) {
        const float* pr = prim + (size_t)(bm * SS + g * 32) * 3;  // uniform
        float d2r[32];
#pragma unroll
        for (int s = 0; s < 32; ++s) {
            const float px = pr[3 * s + 0];      // wave-uniform -> s_load
            const float py = pr[3 * s + 1];
            const float pz = pr[3 * s + 2];
            const float hs = 0.5f * fmaf(pz, pz, fmaf(py, py, px * px));
            float e0 = hq0 + hs;
            e0 = fmaf(px, -q0x, e0);
            e0 = fmaf(py, -q0y, e0);
            e0 = fmaf(pz, -q0z, e0);
            float e1 = hq1 + hs;
            e1 = fmaf(px, -q1x, e1);
            e1 = fmaf(py, -q1y, e1);
            e1 = fmaf(pz, -q1z, e1);
            d1m0 = fminf(d1m0, e0);
            d1m1 = fminf(d1m1, e1);
            d2r[s] = fminf(e0, e1);
        }

        // --- fold32: 32 vals x 64 lanes -> per-lane 64-lane min, dup x2 ---
        float v16[16];
        {
            const bool hi = (lane & 32) != 0;
#pragma unroll
            for (int k = 0; k < 16; ++k) {
                const float xk = hi ? d2r[k + 16] : d2r[k];
                const float xs = hi ? d2r[k] : d2r[k + 16];
                v16[k] = fminf(xk, __shfl_xor(xs, 32, 64));
            }
        }
        float v8[8];
        {
            const bool hi = (lane & 16) != 0;
#pragma unroll
            for (int k = 0; k < 8; ++k) {
                const float xk = hi ? v16[k + 8] : v16[k];
                const float xs = hi ? v16[k] : v16[k + 8];
                v8[k] = fminf(xk, __shfl_xor(xs, 16, 64));
            }
        }
        float v4[4];
        {
            const bool hi = (lane & 8) != 0;
#pragma unroll
            for (int k = 0; k < 4; ++k) {
                const float xk = hi ? v8[k + 4] : v8[k];
                const float xs = hi ? v8[k] : v8[k + 4];
                v4[k] = fminf(xk, __shfl_xor(xs, 8, 64));
            }
        }
        float v2a, v2b;
        {
            const bool hi = (lane & 4) != 0;
            const float xk0 = hi ? v4[2] : v4[0];
            const float xs0 = hi ? v4[0] : v4[2];
            v2a = fminf(xk0, __shfl_xor(xs0, 4, 64));
            const float xk1 = hi ? v4[3] : v4[1];
            const float xs1 = hi ? v4[1] : v4[3];
            v2b = fminf(xk1, __shfl_xor(xs1, 4, 64));
        }
        float v1;
        {
            const bool hi = (lane & 2) != 0;
            const float xk = hi ? v2b : v2a;
            const float xs = hi ? v2a : v2b;
            v1 = fminf(xk, __shfl_xor(xs, 2, 64));
        }
        float r = fminf(v1, __shfl_xor(v1, 1, 64));   // dup x2: lanes {2s,2s+1}
        r = fmaxf(r, 0.0f);                           // keep uint order == float order
        if ((lane & 1) == 0)
            atomicMin(&d2min[(unsigned)(g * 32 + (lane >> 1)) * 256 + bm],
                      __float_as_uint(r));
    }

    // d1: min over all 128 s complete in-block; coalesced e-scale write
    d1[(size_t)bm * NN + n0 + tid]       = d1m0;
    d1[(size_t)bm * NN + n0 + tid + 256] = d1m1;
}

// ---------------------------------------------------------------------------
// Kernel B: p2p sort + stick-breaking; last block finalizes (incl. d2 sums
// from d2min — kernel boundary guarantees atomicMin visibility).
// grid 128 x 256; one thread per (b,n).
// ---------------------------------------------------------------------------
__global__ __launch_bounds__(256) void p2p_final_kernel(
    const float* __restrict__ d1,           // [256][2048] (e-scale)
    const float* __restrict__ probs,        // (B,M)
    const float* __restrict__ size_,        // (B,M,3)
    const unsigned int* __restrict__ d2min, // [128][256]
    float* __restrict__ partial,            // [128]
    unsigned int* __restrict__ counter,
    float* __restrict__ out)                // (4)
{
    const int tid = threadIdx.x;
    const int gid = blockIdx.x * 256 + tid;   // b*N + n
    const int b   = gid >> 11;
    const int n   = gid & (NN - 1);

    float d[16], p[16];
#pragma unroll
    for (int m = 0; m < 16; ++m) {
        const float mn = d1[((size_t)(b * MM + m)) * NN + n];
        d[m] = mn + mn;                       // e -> d
    }

    const float* pb = probs + b * MM;
#pragma unroll
    for (int k = 0; k < 16; ++k) p[k] = pb[k];

#define CE(i, j)                                              \
    {                                                         \
        const bool c = d[i] > d[j];                           \
        const float td = c ? d[j] : d[i];                     \
        d[j] = c ? d[i] : d[j];  d[i] = td;                   \
        const float tp = c ? p[j] : p[i];                     \
        p[j] = c ? p[i] : p[j];  p[i] = tp;                   \
    }
#pragma unroll
    for (int r = 0; r < 16; ++r) {
        if ((r & 1) == 0) {
            CE(0, 1) CE(2, 3) CE(4, 5) CE(6, 7)
            CE(8, 9) CE(10, 11) CE(12, 13) CE(14, 15)
        } else {
            CE(1, 2) CE(3, 4) CE(5, 6) CE(7, 8)
            CE(9, 10) CE(11, 12) CE(13, 14)
        }
    }
#undef CE

    float acc = 1.0f, sum = 0.0f;
#pragma unroll
    for (int k = 0; k < 16; ++k) {
        sum += d[k] * p[k] * acc;
        acc *= (1.0f - p[k]);
    }

    const int wid  = tid >> 6;
    const int lane = tid & 63;
    __shared__ float red4[4];
#pragma unroll
    for (int off = 32; off > 0; off >>= 1)
        sum += __shfl_down(sum, off, 64);
    if (lane == 0) red4[wid] = sum;
    __syncthreads();

    __shared__ bool amLast;
    if (tid == 0) {
        const float bsum = red4[0] + red4[1] + red4[2] + red4[3];
        __hip_atomic_store(&partial[blockIdx.x], bsum,
                           __ATOMIC_RELEASE, __HIP_MEMORY_SCOPE_AGENT);
        const unsigned int prev = __hip_atomic_fetch_add(
            counter, 1u, __ATOMIC_ACQ_REL, __HIP_MEMORY_SCOPE_AGENT);
        amLast = (prev == 127u);
    }
    __syncthreads();
    if (!amLast) return;

    // ---- finalize (one block; tid == b*16 + m) ----
    const int fb = tid >> 4;

    __shared__ float  areaSh[256];
    __shared__ double redA[4];
    __shared__ double redB[4];

    const float s0 = size_[tid * 3 + 0];
    const float s1 = size_[tid * 3 + 1];
    const float s2 = size_[tid * 3 + 2];
    const float inner = powf(s0 * s1, 1.6f) * (1.0f / 3.0f)
                      + powf(s0 * s2, 1.6f) * (1.0f / 3.0f)
                      + powf(s1 * s2, 1.6f) * (1.0f / 3.0f);
    const float a = kFourPi * powf(inner, 0.625f);
    areaSh[tid] = a;
    __syncthreads();

    float asum = 0.0f;
#pragma unroll
    for (int mm = 0; mm < 16; ++mm) asum += areaSh[fb * 16 + mm];
    const float anorm = 16.0f * a / asum;   // M * area / sum_m area

    // d2: sum the e-scale mins over s (coalesced rows), clamp, e->d via x2
    float dsum = 0.0f;
#pragma unroll 8
    for (int k = 0; k < 128; ++k) {
        float v = __uint_as_float(d2min[(unsigned)k * 256 + tid]);
        if (v >= 5.0e29f) v = 0.0f;         // clamp (also kills 0x7f sentinel)
        dsum += v;
    }
    // mean_s(d) = 2 * dsum / 128 = dsum / 64
    double t = (double)(dsum * (1.0f / 64.0f)) * (double)probs[tid] * (double)anorm;
#pragma unroll
    for (int off = 32; off > 0; off >>= 1)
        t += __shfl_down(t, off, 64);
    if (lane == 0) redA[wid] = t;

    double u = 0.0;
    if (tid < 128) {
        const float pv = __hip_atomic_load(&partial[tid],
                                           __ATOMIC_ACQUIRE, __HIP_MEMORY_SCOPE_AGENT);
        u = (double)pv;
    }
#pragma unroll
    for (int off = 32; off > 0; off >>= 1)
        u += __shfl_down(u, off, 64);
    if (lane == 0) redB[wid] = u;

    __syncthreads();
    if (tid == 0) {
        const double prim_to_pcl = (redA[0] + redA[1] + redA[2] + redA[3]) / 256.0;    // /(B*M)
        const double pcl_to_prim = (redB[0] + redB[1] + redB[2] + redB[3]) / 32768.0;  // /(B*N)
        out[0] = (float)(pcl_to_prim + prim_to_pcl);
        out[1] = (float)pcl_to_prim;
        out[2] = (float)prim_to_pcl;
        out[3] = 0.0f;
    }
}

// ---------------------------------------------------------------------------

extern "C" void kernel_launch(void* const* d_in, const int* in_sizes, int n_in,
                              void* d_out, int out_size, void* d_ws, size_t ws_size,
                              hipStream_t stream) {
    const float* pcl   = (const float*)d_in[0];  // (B,N,M,3)
    const float* prim  = (const float*)d_in[1];  // (B,M,S,3)
    const float* size_ = (const float*)d_in[2];  // (B,M,3)
    const float* probs = (const float*)d_in[3];  // (B,M)
    float* out = (float*)d_out;

    float*        d1      = (float*)d_ws;                     // 2 MiB
    unsigned int* d2min   = (unsigned int*)(d1 + (size_t)256 * NN);  // 128 KiB
    float*        partial = (float*)(d2min + 128 * 256);      // 128
    unsigned int* counter = (unsigned int*)(partial + 128);   // 1

    // init d2min to large-positive float (0x7f7f7f7f = 3.39e38) for atomicMin
    hipMemsetAsync(d2min, 0x7f, (size_t)128 * 256 * sizeof(unsigned int), stream);

    dist_kernel<<<dim3(BB * MM, 4), 256, 0, stream>>>(pcl, prim, d1, d2min, counter);
    p2p_final_kernel<<<128, 256, 0, stream>>>(d1, probs, size_, d2min, partial, counter, out);
}

// Round 11
// 119.871 us; speedup vs baseline: 1.2343x; 1.2343x over previous
//
#include <hip/hip_runtime.h>
#include <math.h>

#define BB 16
#define NN 2048
#define MM 16
#define SS 128

__constant__ const float kFourPi = 12.566370614359172f;

// ---------------------------------------------------------------------------
// Kernel A: grid (256 bm, 4 n-chunks) x 256 threads, 4 blocks/CU.
// ZERO LDS, ZERO barriers, and — the R10 fix — SPILL-PROOF at the
// compiler's 64-VGPR budget: d2 fold processes s in groups of 8
// (d2r[8] + v4[4] peak ~40 live VGPRs; R10's d2r[32]+v16[16] spilled).
// Fold8: masks 32,16,8 move s-bits[2:0] into lane-bits[5:3]; xor 4,2,1
// complete the 64-lane min (dup x8; representative lane = s_local*8).
// prim read via wave-uniform pointer -> s_load. e = d/2 dot expansion.
// d1 (e-scale) finished in-block; d2 via uint-punned global atomicMin.
// ---------------------------------------------------------------------------
__global__ __launch_bounds__(256, 4) void dist_kernel(
    const float* __restrict__ pcl,     // (B,N,M,3)
    const float* __restrict__ prim,    // (B,M,S,3)
    float* __restrict__ d1,            // [256][2048] (e-scale)
    unsigned int* __restrict__ d2min,  // [128][256]  (e-scale, uint-punned)
    unsigned int* __restrict__ counter)
{
    const int bm    = blockIdx.x;
    const int chunk = blockIdx.y;
    const int b     = bm >> 4;
    const int m     = bm & 15;
    const int tid   = threadIdx.x;
    const int lane  = tid & 63;

    if (bm == 0 && chunk == 0 && tid == 0)
        __hip_atomic_store(counter, 0u, __ATOMIC_RELAXED, __HIP_MEMORY_SCOPE_AGENT);

    const int n0 = chunk * 512;
    // two pcl points per thread, scattered 12B loads (read exactly once)
    const float* q0p = pcl + ((size_t)(b * NN + n0 + tid) * MM + m) * 3;
    const float* q1p = q0p + (size_t)256 * MM * 3;
    const float q0x = q0p[0], q0y = q0p[1], q0z = q0p[2];
    const float q1x = q1p[0], q1y = q1p[1], q1z = q1p[2];
    const float hq0 = 0.5f * (q0x * q0x + q0y * q0y + q0z * q0z);
    const float hq1 = 0.5f * (q1x * q1x + q1y * q1y + q1z * q1z);

    float d1m0 = 3.0e38f, d1m1 = 3.0e38f;

    // 16 groups of 8 s
#pragma unroll 2
    for (int g = 0; g < 16; ++g) {
        const float* pr = prim + (size_t)(bm * SS + g * 8) * 3;  // wave-uniform
        float d2r[8];
#pragma unroll
        for (int s = 0; s < 8; ++s) {
            const float px = pr[3 * s + 0];      // s_load (scalar cache)
            const float py = pr[3 * s + 1];
            const float pz = pr[3 * s + 2];
            const float hs = 0.5f * fmaf(pz, pz, fmaf(py, py, px * px));
            float e0 = hq0 + hs;
            e0 = fmaf(px, -q0x, e0);
            e0 = fmaf(py, -q0y, e0);
            e0 = fmaf(pz, -q0z, e0);
            float e1 = hq1 + hs;
            e1 = fmaf(px, -q1x, e1);
            e1 = fmaf(py, -q1y, e1);
            e1 = fmaf(pz, -q1z, e1);
            d1m0 = fminf(d1m0, e0);
            d1m1 = fminf(d1m1, e1);
            d2r[s] = fminf(e0, e1);
        }

        // --- fold8: 8 vals x 64 lanes -> 64-lane min per s, dup x8 ---
        float v4[4];
        {
            const bool hi = (lane & 32) != 0;
#pragma unroll
            for (int k = 0; k < 4; ++k) {
                const float xk = hi ? d2r[k + 4] : d2r[k];
                const float xs = hi ? d2r[k] : d2r[k + 4];
                v4[k] = fminf(xk, __shfl_xor(xs, 32, 64));
            }
        }
        float v2a, v2b;
        {
            const bool hi = (lane & 16) != 0;
            const float xk0 = hi ? v4[2] : v4[0];
            const float xs0 = hi ? v4[0] : v4[2];
            v2a = fminf(xk0, __shfl_xor(xs0, 16, 64));
            const float xk1 = hi ? v4[3] : v4[1];
            const float xs1 = hi ? v4[1] : v4[3];
            v2b = fminf(xk1, __shfl_xor(xs1, 16, 64));
        }
        float v1;
        {
            const bool hi = (lane & 8) != 0;
            const float xk = hi ? v2b : v2a;
            const float xs = hi ? v2a : v2b;
            v1 = fminf(xk, __shfl_xor(xs, 8, 64));
        }
        v1 = fminf(v1, __shfl_xor(v1, 4, 64));
        v1 = fminf(v1, __shfl_xor(v1, 2, 64));
        v1 = fminf(v1, __shfl_xor(v1, 1, 64));   // dup x8: s_local = lane bits[5:3]
        const float r = fmaxf(v1, 0.0f);         // uint order == float order
        if ((lane & 7) == 0)
            atomicMin(&d2min[(unsigned)(g * 8 + (lane >> 3)) * 256 + bm],
                      __float_as_uint(r));
    }

    // d1: min over all 128 s complete in-block; coalesced e-scale write
    d1[(size_t)bm * NN + n0 + tid]       = d1m0;
    d1[(size_t)bm * NN + n0 + tid + 256] = d1m1;
}

// ---------------------------------------------------------------------------
// Kernel B: p2p sort + stick-breaking; last block finalizes (d2 sums read
// from d2min — kernel boundary guarantees atomicMin visibility).
// grid 256 x 128; one thread per (b,n).  finalize needs >=256 threads'
// worth of (b,m) work -> done by 128 threads handling 2 each.
// ---------------------------------------------------------------------------
__global__ __launch_bounds__(128) void p2p_final_kernel(
    const float* __restrict__ d1,           // [256][2048] (e-scale)
    const float* __restrict__ probs,        // (B,M)
    const float* __restrict__ size_,        // (B,M,3)
    const unsigned int* __restrict__ d2min, // [128][256]
    float* __restrict__ partial,            // [256]
    unsigned int* __restrict__ counter,
    float* __restrict__ out)                // (4)
{
    const int tid = threadIdx.x;
    const int gid = blockIdx.x * 128 + tid;   // b*N + n
    const int b   = gid >> 11;
    const int n   = gid & (NN - 1);

    float d[16], p[16];
#pragma unroll
    for (int m = 0; m < 16; ++m) {
        const float mn = d1[((size_t)(b * MM + m)) * NN + n];
        d[m] = mn + mn;                       // e -> d
    }

    const float* pb = probs + b * MM;
#pragma unroll
    for (int k = 0; k < 16; ++k) p[k] = pb[k];

#define CE(i, j)                                              \
    {                                                         \
        const bool c = d[i] > d[j];                           \
        const float td = c ? d[j] : d[i];                     \
        d[j] = c ? d[i] : d[j];  d[i] = td;                   \
        const float tp = c ? p[j] : p[i];                     \
        p[j] = c ? p[i] : p[j];  p[i] = tp;                   \
    }
#pragma unroll
    for (int r = 0; r < 16; ++r) {
        if ((r & 1) == 0) {
            CE(0, 1) CE(2, 3) CE(4, 5) CE(6, 7)
            CE(8, 9) CE(10, 11) CE(12, 13) CE(14, 15)
        } else {
            CE(1, 2) CE(3, 4) CE(5, 6) CE(7, 8)
            CE(9, 10) CE(11, 12) CE(13, 14)
        }
    }
#undef CE

    float acc = 1.0f, sum = 0.0f;
#pragma unroll
    for (int k = 0; k < 16; ++k) {
        sum += d[k] * p[k] * acc;
        acc *= (1.0f - p[k]);
    }

    const int wid  = tid >> 6;   // 0,1
    const int lane = tid & 63;
    __shared__ float red2[2];
#pragma unroll
    for (int off = 32; off > 0; off >>= 1)
        sum += __shfl_down(sum, off, 64);
    if (lane == 0) red2[wid] = sum;
    __syncthreads();

    __shared__ bool amLast;
    if (tid == 0) {
        const float bsum = red2[0] + red2[1];
        __hip_atomic_store(&partial[blockIdx.x], bsum,
                           __ATOMIC_RELEASE, __HIP_MEMORY_SCOPE_AGENT);
        const unsigned int prev = __hip_atomic_fetch_add(
            counter, 1u, __ATOMIC_ACQ_REL, __HIP_MEMORY_SCOPE_AGENT);
        amLast = (prev == 255u);
    }
    __syncthreads();
    if (!amLast) return;

    // ---- finalize: 128 threads, each handles bm = tid and bm = tid+128 ----
    __shared__ float  areaSh[256];
    __shared__ double redA[2];
    __shared__ double redB[2];

#pragma unroll
    for (int h = 0; h < 2; ++h) {
        const int bm = tid + h * 128;
        const float s0 = size_[bm * 3 + 0];
        const float s1 = size_[bm * 3 + 1];
        const float s2 = size_[bm * 3 + 2];
        const float inner = powf(s0 * s1, 1.6f) * (1.0f / 3.0f)
                          + powf(s0 * s2, 1.6f) * (1.0f / 3.0f)
                          + powf(s1 * s2, 1.6f) * (1.0f / 3.0f);
        areaSh[bm] = kFourPi * powf(inner, 0.625f);
    }
    __syncthreads();

    double t = 0.0;
#pragma unroll
    for (int h = 0; h < 2; ++h) {
        const int bm = tid + h * 128;
        const int fb = bm >> 4;
        float asum = 0.0f;
#pragma unroll
        for (int mm = 0; mm < 16; ++mm) asum += areaSh[fb * 16 + mm];
        const float anorm = 16.0f * areaSh[bm] / asum;   // M*area/sum

        float dsum = 0.0f;
#pragma unroll 8
        for (int k = 0; k < 128; ++k) {
            float v = __uint_as_float(d2min[(unsigned)k * 256 + bm]);
            if (v >= 5.0e29f) v = 0.0f;      // clamp (also kills sentinel)
            dsum += v;
        }
        // mean_s(d) = 2*dsum/128 = dsum/64
        t += (double)(dsum * (1.0f / 64.0f)) * (double)probs[bm] * (double)anorm;
    }
#pragma unroll
    for (int off = 32; off > 0; off >>= 1)
        t += __shfl_down(t, off, 64);
    if (lane == 0) redA[wid] = t;

    double u = 0.0;
    {
        const float pv0 = __hip_atomic_load(&partial[tid],
                                            __ATOMIC_ACQUIRE, __HIP_MEMORY_SCOPE_AGENT);
        const float pv1 = __hip_atomic_load(&partial[tid + 128],
                                            __ATOMIC_ACQUIRE, __HIP_MEMORY_SCOPE_AGENT);
        u = (double)pv0 + (double)pv1;
    }
#pragma unroll
    for (int off = 32; off > 0; off >>= 1)
        u += __shfl_down(u, off, 64);
    if (lane == 0) redB[wid] = u;

    __syncthreads();
    if (tid == 0) {
        const double prim_to_pcl = (redA[0] + redA[1]) / 256.0;    // /(B*M)
        const double pcl_to_prim = (redB[0] + redB[1]) / 32768.0;  // /(B*N)
        out[0] = (float)(pcl_to_prim + prim_to_pcl);
        out[1] = (float)pcl_to_prim;
        out[2] = (float)prim_to_pcl;
        out[3] = 0.0f;
    }
}

// ---------------------------------------------------------------------------

extern "C" void kernel_launch(void* const* d_in, const int* in_sizes, int n_in,
                              void* d_out, int out_size, void* d_ws, size_t ws_size,
                              hipStream_t stream) {
    const float* pcl   = (const float*)d_in[0];  // (B,N,M,3)
    const float* prim  = (const float*)d_in[1];  // (B,M,S,3)
    const float* size_ = (const float*)d_in[2];  // (B,M,3)
    const float* probs = (const float*)d_in[3];  // (B,M)
    float* out = (float*)d_out;

    float*        d1      = (float*)d_ws;                            // 2 MiB
    unsigned int* d2min   = (unsigned int*)(d1 + (size_t)256 * NN);  // 128 KiB
    float*        partial = (float*)(d2min + 128 * 256);             // 256
    unsigned int* counter = (unsigned int*)(partial + 256);          // 1

    // init d2min to large-positive float (0x7f7f7f7f = 3.39e38) for atomicMin
    hipMemsetAsync(d2min, 0x7f, (size_t)128 * 256 * sizeof(unsigned int), stream);

    dist_kernel<<<dim3(BB * MM, 4), 256, 0, stream>>>(pcl, prim, d1, d2min, counter);
    p2p_final_kernel<<<256, 128, 0, stream>>>(d1, probs, size_, d2min, partial, counter, out);
}

// Round 12
// 89.532 us; speedup vs baseline: 1.6526x; 1.3389x over previous
//
#include <hip/hip_runtime.h>
#include <math.h>

#define BB 16
#define NN 2048
#define MM 16
#define SS 128

__constant__ const float kFourPi = 12.566370614359172f;

// ---------------------------------------------------------------------------
// Kernel A: one block per (b,m), 1024 threads (16 waves), 1 block/CU.
// (Best-measured config: R8, 89.4 us total.)
// Stages pcl[b,:,m,:] (+0.5|q|^2) and prim[b,m] (+0.5|p|^2) in LDS once.
// 4 s-subgroups x 256 threads; thread: 8 n in regs, 32 s loop, e = d/2 via
// dot expansion. d2 via register d2r[32] + dimension-fold (zero cross-lane
// ops in hot loop). Writes d1[bm][n] (e-scale, 2 MB) and d2sum[bm] directly.
// ---------------------------------------------------------------------------
__global__ __launch_bounds__(1024, 4) void fused_dist_kernel(
    const float* __restrict__ pcl,    // (B,N,M,3)
    const float* __restrict__ prim,   // (B,M,S,3)
    float* __restrict__ d1,           // [256][2048]  (e-scale)
    float* __restrict__ d2sum,        // [256]        (d-scale)
    unsigned int* __restrict__ counter)
{
    const int bm  = blockIdx.x;
    const int b   = bm >> 4;
    const int m   = bm & 15;
    const int tid = threadIdx.x;

    __shared__ float  Qx[NN], Qy[NN], Qz[NN], Qh[NN];  // 32 KB
    __shared__ float4 Plds[SS];                        // 2 KB (x,y,z,hp)
    __shared__ float  d1s[4][NN];                      // 32 KB
    __shared__ float  wred[16][64];                    // 4 KB
    __shared__ float  rsum[4];

    if (bm == 0 && tid == 0)
        __hip_atomic_store(counter, 0u, __ATOMIC_RELAXED, __HIP_MEMORY_SCOPE_AGENT);

    // stage pcl[b,:,m,:] (12B-of-192B scatter, read exactly once) + hq
    {
        const size_t base = ((size_t)(b * NN) * MM + m) * 3;
#pragma unroll
        for (int j = 0; j < 2; ++j) {
            const int n = tid + j * 1024;
            const float* q = pcl + base + (size_t)n * (MM * 3);
            const float x = q[0], y = q[1], z = q[2];
            Qx[n] = x; Qy[n] = y; Qz[n] = z;
            Qh[n] = 0.5f * (x * x + y * y + z * z);
        }
    }
    if (tid < SS) {
        const float* pp = prim + ((size_t)bm * SS + tid) * 3;
        const float x = pp[0], y = pp[1], z = pp[2];
        Plds[tid] = make_float4(x, y, z, 0.5f * (x * x + y * y + z * z));
    }
    __syncthreads();

    const int sub  = tid >> 8;    // s-chunk 0..3
    const int stid = tid & 255;
    const int s0   = sub * 32;
    const int wid  = tid >> 6;    // 0..15
    const int lane = tid & 63;

    float qx[8], qy[8], qz[8], hq[8], d1m[8];
#pragma unroll
    for (int j = 0; j < 8; ++j) {
        const int n = stid + j * 256;
        qx[j] = Qx[n]; qy[j] = Qy[n]; qz[j] = Qz[n]; hq[j] = Qh[n];
        d1m[j] = 3.0e38f;
    }

    float d2r[32];
#pragma unroll
    for (int s = 0; s < 32; ++s) {
        const float4 f = Plds[s0 + s];         // wave-uniform ds_read_b128
        float e[8];
#pragma unroll
        for (int j = 0; j < 8; ++j) {
            float t = hq[j] + f.w;             // 0.5|q|^2 + 0.5|p|^2
            t = fmaf(f.x, -qx[j], t);
            t = fmaf(f.y, -qy[j], t);
            t = fmaf(f.z, -qz[j], t);
            e[j] = t;
            d1m[j] = fminf(d1m[j], t);
        }
        const float m01 = fminf(e[0], e[1]);
        const float m23 = fminf(e[2], e[3]);
        const float m45 = fminf(e[4], e[5]);
        const float m67 = fminf(e[6], e[7]);
        d2r[s] = fminf(fminf(m01, m23), fminf(m45, m67));
    }

    // d1: combine 4 s-chunks in LDS, coalesced e-scale global write
#pragma unroll
    for (int j = 0; j < 8; ++j)
        d1s[sub][stid + j * 256] = d1m[j];
    __syncthreads();
#pragma unroll
    for (int j = 0; j < 2; ++j) {
        const int n = tid + j * 1024;
        d1[(size_t)bm * NN + n] = fminf(fminf(d1s[0][n], d1s[1][n]),
                                        fminf(d1s[2][n], d1s[3][n]));
    }

    // --- d2: dimension-folding wave reduction (32 vals -> 1 per lane) ---
    float v16[16];
    {
        const bool hi = (lane & 32) != 0;
#pragma unroll
        for (int k = 0; k < 16; ++k) {
            const float xk = hi ? d2r[k + 16] : d2r[k];
            const float xs = hi ? d2r[k] : d2r[k + 16];
            v16[k] = fminf(xk, __shfl_xor(xs, 32, 64));
        }
    }
    float v8[8];
    {
        const bool hi = (lane & 16) != 0;
#pragma unroll
        for (int k = 0; k < 8; ++k) {
            const float xk = hi ? v16[k + 8] : v16[k];
            const float xs = hi ? v16[k] : v16[k + 8];
            v8[k] = fminf(xk, __shfl_xor(xs, 16, 64));
        }
    }
    float v4[4];
    {
        const bool hi = (lane & 8) != 0;
#pragma unroll
        for (int k = 0; k < 4; ++k) {
            const float xk = hi ? v8[k + 4] : v8[k];
            const float xs = hi ? v8[k] : v8[k + 4];
            v4[k] = fminf(xk, __shfl_xor(xs, 8, 64));
        }
    }
    float v2a, v2b;
    {
        const bool hi = (lane & 4) != 0;
        const float xk0 = hi ? v4[2] : v4[0];
        const float xs0 = hi ? v4[0] : v4[2];
        v2a = fminf(xk0, __shfl_xor(xs0, 4, 64));
        const float xk1 = hi ? v4[3] : v4[1];
        const float xs1 = hi ? v4[1] : v4[3];
        v2b = fminf(xk1, __shfl_xor(xs1, 4, 64));
    }
    float v1;
    {
        const bool hi = (lane & 2) != 0;
        const float xk = hi ? v2b : v2a;
        const float xs = hi ? v2a : v2b;
        v1 = fminf(xk, __shfl_xor(xs, 2, 64));
    }
    // lane holds min over its wave's 512 n for s = s0 + bits[5:1], dup x2
    const float r = fminf(v1, __shfl_xor(v1, 1, 64));
    wred[wid][lane] = r;
    __syncthreads();

    // combine the 4 waves of each sub-group (-> min over all 2048 n), clamp,
    // sum: 64-lane sum = 2 * sum_s e_min = sum_s d_min  (x2 dup cancels)
    if (tid < 256) {                 // waves 0..3, fully active
        const int sc = tid >> 6;     // s-chunk this wave combines
        const int l  = tid & 63;
        float mv = fminf(fminf(wred[sc * 4 + 0][l], wred[sc * 4 + 1][l]),
                         fminf(wred[sc * 4 + 2][l], wred[sc * 4 + 3][l]));
        if (mv >= 5.0e29f) mv = 0.0f;          // clamp at e-scale (d >= 1e30)
#pragma unroll
        for (int off = 32; off > 0; off >>= 1)
            mv += __shfl_down(mv, off, 64);
        if (l == 0) rsum[sc] = mv;
    }
    __syncthreads();
    if (tid == 0) d2sum[bm] = rsum[0] + rsum[1] + rsum[2] + rsum[3];
}

// ---------------------------------------------------------------------------
// Kernel B: p2p sort + stick-breaking; last block finalizes.
// grid 128 x 256; one thread per (b,n).
// ---------------------------------------------------------------------------
__global__ __launch_bounds__(256) void p2p_final_kernel(
    const float* __restrict__ d1,      // [256][2048] (e-scale)
    const float* __restrict__ probs,   // (B,M)
    const float* __restrict__ size_,   // (B,M,3)
    const float* __restrict__ d2sum,   // [256]
    float* __restrict__ partial,       // [128]
    unsigned int* __restrict__ counter,
    float* __restrict__ out)           // (4)
{
    const int tid = threadIdx.x;
    const int gid = blockIdx.x * 256 + tid;   // b*N + n
    const int b   = gid >> 11;
    const int n   = gid & (NN - 1);

    float d[16], p[16];
#pragma unroll
    for (int m = 0; m < 16; ++m) {
        const float mn = d1[((size_t)(b * MM + m)) * NN + n];
        d[m] = mn + mn;                       // e -> d
    }

    const float* pb = probs + b * MM;
#pragma unroll
    for (int k = 0; k < 16; ++k) p[k] = pb[k];

#define CE(i, j)                                              \
    {                                                         \
        const bool c = d[i] > d[j];                           \
        const float td = c ? d[j] : d[i];                     \
        d[j] = c ? d[i] : d[j];  d[i] = td;                   \
        const float tp = c ? p[j] : p[i];                     \
        p[j] = c ? p[i] : p[j];  p[i] = tp;                   \
    }
#pragma unroll
    for (int r = 0; r < 16; ++r) {
        if ((r & 1) == 0) {
            CE(0, 1) CE(2, 3) CE(4, 5) CE(6, 7)
            CE(8, 9) CE(10, 11) CE(12, 13) CE(14, 15)
        } else {
            CE(1, 2) CE(3, 4) CE(5, 6) CE(7, 8)
            CE(9, 10) CE(11, 12) CE(13, 14)
        }
    }
#undef CE

    float acc = 1.0f, sum = 0.0f;
#pragma unroll
    for (int k = 0; k < 16; ++k) {
        sum += d[k] * p[k] * acc;
        acc *= (1.0f - p[k]);
    }

    const int wid  = tid >> 6;
    const int lane = tid & 63;
    __shared__ float red4[4];
#pragma unroll
    for (int off = 32; off > 0; off >>= 1)
        sum += __shfl_down(sum, off, 64);
    if (lane == 0) red4[wid] = sum;
    __syncthreads();

    __shared__ bool amLast;
    if (tid == 0) {
        const float bsum = red4[0] + red4[1] + red4[2] + red4[3];
        __hip_atomic_store(&partial[blockIdx.x], bsum,
                           __ATOMIC_RELEASE, __HIP_MEMORY_SCOPE_AGENT);
        const unsigned int prev = __hip_atomic_fetch_add(
            counter, 1u, __ATOMIC_ACQ_REL, __HIP_MEMORY_SCOPE_AGENT);
        amLast = (prev == 127u);
    }
    __syncthreads();
    if (!amLast) return;

    // ---- finalize (one block; tid == b*16 + m) ----
    const int fb = tid >> 4;

    __shared__ float  areaSh[256];
    __shared__ double redA[4];
    __shared__ double redB[4];

    const float s0 = size_[tid * 3 + 0];
    const float s1 = size_[tid * 3 + 1];
    const float s2 = size_[tid * 3 + 2];
    const float inner = powf(s0 * s1, 1.6f) * (1.0f / 3.0f)
                      + powf(s0 * s2, 1.6f) * (1.0f / 3.0f)
                      + powf(s1 * s2, 1.6f) * (1.0f / 3.0f);
    const float a = kFourPi * powf(inner, 0.625f);
    areaSh[tid] = a;
    __syncthreads();

    float asum = 0.0f;
#pragma unroll
    for (int mm = 0; mm < 16; ++mm) asum += areaSh[fb * 16 + mm];
    const float anorm = 16.0f * a / asum;   // M * area / sum_m area

    double t = (double)(d2sum[tid] * (1.0f / 128.0f)) * (double)probs[tid] * (double)anorm;
#pragma unroll
    for (int off = 32; off > 0; off >>= 1)
        t += __shfl_down(t, off, 64);
    if (lane == 0) redA[wid] = t;

    double u = 0.0;
    if (tid < 128) {
        const float pv = __hip_atomic_load(&partial[tid],
                                           __ATOMIC_ACQUIRE, __HIP_MEMORY_SCOPE_AGENT);
        u = (double)pv;
    }
#pragma unroll
    for (int off = 32; off > 0; off >>= 1)
        u += __shfl_down(u, off, 64);
    if (lane == 0) redB[wid] = u;

    __syncthreads();
    if (tid == 0) {
        const double prim_to_pcl = (redA[0] + redA[1] + redA[2] + redA[3]) / 256.0;    // /(B*M)
        const double pcl_to_prim = (redB[0] + redB[1] + redB[2] + redB[3]) / 32768.0;  // /(B*N)
        out[0] = (float)(pcl_to_prim + prim_to_pcl);
        out[1] = (float)pcl_to_prim;
        out[2] = (float)prim_to_pcl;
        out[3] = 0.0f;
    }
}

// ---------------------------------------------------------------------------

extern "C" void kernel_launch(void* const* d_in, const int* in_sizes, int n_in,
                              void* d_out, int out_size, void* d_ws, size_t ws_size,
                              hipStream_t stream) {
    const float* pcl   = (const float*)d_in[0];  // (B,N,M,3)
    const float* prim  = (const float*)d_in[1];  // (B,M,S,3)
    const float* size_ = (const float*)d_in[2];  // (B,M,3)
    const float* probs = (const float*)d_in[3];  // (B,M)
    float* out = (float*)d_out;

    float* d1             = (float*)d_ws;             // 256*2048 floats (2 MiB)
    float* d2sum          = d1 + (size_t)256 * NN;    // 256
    float* partial        = d2sum + 256;              // 128
    unsigned int* counter = (unsigned int*)(partial + 128);

    fused_dist_kernel<<<BB * MM, 1024, 0, stream>>>(pcl, prim, d1, d2sum, counter);
    p2p_final_kernel<<<128, 256, 0, stream>>>(d1, probs, size_, d2sum, partial, counter, out);
}